// Round 6
// baseline (129.951 us; speedup 1.0000x reference)
//
#include <hip/hip_runtime.h>
#include <hip/hip_fp16.h>

#define S_N 16
#define T_N 400
#define F_N 16
#define SF_N 250
#define G_N 4
#define OUT_ROW 100400   // 400 + 250*400

typedef _Float16 f16x8 __attribute__((ext_vector_type(8)));
typedef float    f32x4 __attribute__((ext_vector_type(4)));

union QU { uint4 u; f16x8 v; };

// ws layout (bytes), all 16B-aligned:
#define QTAB_OFF   0
#define W2FRAG_OFF 1638400   // 64 lanes * 8 f16  = 1024 B
#define B1H_OFF    1639424   // 32 f16            = 64 B
#define B2F_OFF    1639488   // 16 f32            = 64 B
#define W3F_OFF    1639552   // 16 f32            = 64 B
#define B3F_OFF    1639616   // 1 f32

// ---------------------------------------------------------------------------
// Kernel A: build q-table (fp16) + MFMA-ready weight frags, emit unshuffled
// outputs. grid 100 x 64.
// qtab[s][g][t][k] = sum_{j in grp g} (obs[s,t,j]-mu_j)*A[j][k],
//   A[j][k] = sum_i Sig[i][j]*W1[i][k]
// ---------------------------------------------------------------------------
__global__ __launch_bounds__(64) void precompute_kernel(
    const float* __restrict__ obs,   // (S,T,F)
    const float* __restrict__ mu,    // (F,1)
    const float* __restrict__ Sig,   // (F,F)
    const float* __restrict__ W1,    // (F,32)
    const float* __restrict__ b1,    // (32,)
    const float* __restrict__ W2,    // (32,16)
    const float* __restrict__ b2,    // (16,)
    const float* __restrict__ W3,    // (16,1)
    const float* __restrict__ b3,    // (1,)
    __half* __restrict__ qtab,
    __half* __restrict__ w2frag,     // 64*8 f16, A-frag layout for W2^T
    __half* __restrict__ b1h,        // 32 f16
    float* __restrict__ b2f,         // 16
    float* __restrict__ w3f,         // 16
    float* __restrict__ b3f,         // 1
    float* __restrict__ out)         // (S, OUT_ROW) f32
{
    __shared__ float sAm[512];
    __shared__ float sW2[512];
    __shared__ float sMu[16];
    __shared__ float sB1[32];
    __shared__ float sB2[16];
    __shared__ float sW3[16];
    __shared__ float sB3;

    const int tid = threadIdx.x;   // 0..63

    for (int e = tid; e < 512; e += 64) {
        int j = e >> 5, k = e & 31;
        float acc = 0.f;
        #pragma unroll
        for (int i = 0; i < 16; ++i)
            acc = fmaf(Sig[i * 16 + j], W1[i * 32 + k], acc);
        sAm[e] = acc;
        sW2[e] = W2[e];
    }
    if (tid < 16) sMu[tid] = mu[tid];
    if (tid < 32) sB1[tid] = b1[tid];
    if (tid < 16) sB2[tid] = b2[tid];
    if (tid < 16) sW3[tid] = W3[tid];
    if (tid == 0) sB3 = b3[0];
    __syncthreads();

    if (blockIdx.x == 0) {
        // A-frag for A = W2^T: lane l holds A[m=l&15][k=(l>>4)*8+j] = W2[k][m]
        {
            int n = tid & 15, cc = tid >> 4;
            #pragma unroll
            for (int j = 0; j < 8; ++j)
                w2frag[tid * 8 + j] = __float2half(sW2[(cc * 8 + j) * 16 + n]);
        }
        if (tid < 32) b1h[tid] = __float2half(sB1[tid]);
        if (tid < 16) b2f[tid] = sB2[tid];
        if (tid < 16) w3f[tid] = sW3[tid];
        if (tid == 0) b3f[0] = sB3;
    }

    const int gid = blockIdx.x * 64 + tid;   // 0..6399 == s*400+t
    const int s = gid / T_N;
    const int t = gid - s * T_N;

    float xm[16];
    {
        const float4* op = (const float4*)(obs + (size_t)gid * 16);
        float4 o0 = op[0], o1 = op[1], o2 = op[2], o3 = op[3];
        float v[16] = {o0.x, o0.y, o0.z, o0.w, o1.x, o1.y, o1.z, o1.w,
                       o2.x, o2.y, o2.z, o2.w, o3.x, o3.y, o3.z, o3.w};
        #pragma unroll
        for (int j = 0; j < 16; ++j) xm[j] = v[j] - sMu[j];
    }

    float h1[32];
    #pragma unroll
    for (int k = 0; k < 32; ++k) h1[k] = sB1[k];

    #pragma unroll
    for (int g = 0; g < 4; ++g) {
        float qg[32];
        #pragma unroll
        for (int k = 0; k < 32; ++k) {
            float a = xm[4 * g + 0] * sAm[(4 * g + 0) * 32 + k];
            a = fmaf(xm[4 * g + 1], sAm[(4 * g + 1) * 32 + k], a);
            a = fmaf(xm[4 * g + 2], sAm[(4 * g + 2) * 32 + k], a);
            a = fmaf(xm[4 * g + 3], sAm[(4 * g + 3) * 32 + k], a);
            qg[k] = a;
            h1[k] += a;
        }
        __half2* dst = (__half2*)(qtab + ((size_t)(s * 4 + g) * T_N + t) * 32);
        #pragma unroll
        for (int k2 = 0; k2 < 16; ++k2)
            dst[k2] = __floats2half2_rn(qg[2 * k2], qg[2 * k2 + 1]);
    }

    #pragma unroll
    for (int k = 0; k < 32; ++k) h1[k] = fmaxf(h1[k], 0.01f * h1[k]);

    float h2[16];
    #pragma unroll
    for (int j = 0; j < 16; ++j) h2[j] = sB2[j];
    #pragma unroll
    for (int k = 0; k < 32; ++k) {
        float a = h1[k];
        #pragma unroll
        for (int j = 0; j < 16; ++j) h2[j] = fmaf(a, sW2[k * 16 + j], h2[j]);
    }
    float acc = sB3;
    #pragma unroll
    for (int j = 0; j < 16; ++j) {
        float hj = fmaxf(h2[j], 0.01f * h2[j]);
        acc = fmaf(hj, sW3[j], acc);
    }
    out[(size_t)s * OUT_ROW + t] = 1.f / (1.f + __expf(-acc));
}

// ---------------------------------------------------------------------------
// Kernel B: one wave = 64 consecutive samples; 4x mfma_f32_16x16x32_f16.
// Phases pinned with sched_barrier(0): 4 perm loads || 16 bpermutes ||
// 16 gathers ALL in flight || math. Without the barriers the scheduler
// sinks gathers next to consumers (observed: VGPR=36, serialized rounds).
// grid 6250 x 256 (= 25000 waves x 64 samples = 1,600,000).
// ---------------------------------------------------------------------------
__global__ __launch_bounds__(256, 4) void eval_kernel(
    const int* __restrict__ perm,        // (SF,G,S,T)
    const __half* __restrict__ qtab,     // (S,G,T,32) fp16
    const __half* __restrict__ w2frag,   // 64*8
    const __half* __restrict__ b1h,      // 32
    const float* __restrict__ b2f,       // 16
    const float* __restrict__ w3f,       // 16
    const float* __restrict__ b3p,       // 1
    float* __restrict__ out)             // (S, OUT_ROW)
{
    const int tid  = threadIdx.x;
    const int lane = tid & 63;
    const int m    = lane & 15;   // sample-in-group (B col)
    const int c    = lane >> 4;   // k-chunk / quad
    const int base = (blockIdx.x * 4 + (tid >> 6)) * 64;   // first sample id

    // ---- phase 0: issue all 4 perm loads ----
    int pidx[4];
    int s_q[4];
    #pragma unroll
    for (int q = 0; q < 4; ++q) {
        const int e_m = base + q * 16 + m;
        const int s   = e_m / 100000;            // SF_N*T_N
        const int r1  = e_m - s * 100000;
        const int sf  = r1 / 400;
        const int t   = r1 - sf * 400;
        s_q[q] = s;
        pidx[q] = perm[sf * 25600 + c * 6400 + s * 400 + t];
    }
    __builtin_amdgcn_sched_barrier(0);   // perm loads may not sink below

    const f16x8 afrag = *(const f16x8*)(w2frag + lane * 8);
    const f16x8 b1v   = *(const f16x8*)(b1h + c * 8);
    const float4 b2v  = *(const float4*)(b2f + c * 4);
    const float4 w3v  = *(const float4*)(w3f + c * 4);
    const float  b3   = b3p[0];

    // ---- phase 1: redistribute indices (lane needs all 4 groups for its m) ----
    int idx[4][4];
    #pragma unroll
    for (int q = 0; q < 4; ++q) {
        idx[q][0] = __shfl(pidx[q], m);
        idx[q][1] = __shfl(pidx[q], 16 + m);
        idx[q][2] = __shfl(pidx[q], 32 + m);
        idx[q][3] = __shfl(pidx[q], 48 + m);
    }

    // ---- phase 2: issue all 16 gathers; lanes m,m+16,m+32,m+48 share a row ----
    QU a[4][4];
    #pragma unroll
    for (int q = 0; q < 4; ++q) {
        const size_t rb = (size_t)s_q[q] * 1600;
        #pragma unroll
        for (int g = 0; g < 4; ++g)
            a[q][g].u = *(const uint4*)(qtab + (rb + g * 400 + idx[q][g]) * 32 + c * 8);
    }
    __builtin_amdgcn_sched_barrier(0);   // all 16 gathers in flight before math

    // ---- phase 3: math ----
    float res0, res1, res2, res3;
    #pragma unroll
    for (int q = 0; q < 4; ++q) {
        // h1 chunk = q0+q1+q2+q3 + b1 (v_pk_add_f16), then leaky relu
        f16x8 h = (a[q][0].v + a[q][1].v) + (a[q][2].v + a[q][3].v) + b1v;
        #pragma unroll
        for (int k = 0; k < 8; ++k) {
            _Float16 x = h[k];
            _Float16 y = x * (_Float16)0.01f;
            h[k] = x > y ? x : y;     // max(x, 0.01x) -> v_(pk_)max_f16
        }

        // D[unit][sample] = W2^T(16x32) * h1^T(32x16)
        f32x4 acc = {0.f, 0.f, 0.f, 0.f};
        acc = __builtin_amdgcn_mfma_f32_16x16x32_f16(afrag, h, acc, 0, 0, 0);

        // layer 3: lane holds units c*4+r for its sample; partial dot, then
        // reduce across the 4 c-groups (lanes m, m+16, m+32, m+48).
        float p;
        {
            float v0 = acc[0] + b2v.x; v0 = fmaxf(v0, 0.01f * v0); p = v0 * w3v.x;
            float v1 = acc[1] + b2v.y; v1 = fmaxf(v1, 0.01f * v1); p = fmaf(v1, w3v.y, p);
            float v2 = acc[2] + b2v.z; v2 = fmaxf(v2, 0.01f * v2); p = fmaf(v2, w3v.z, p);
            float v3 = acc[3] + b2v.w; v3 = fmaxf(v3, 0.01f * v3); p = fmaf(v3, w3v.w, p);
        }
        p += __shfl_xor(p, 16);
        p += __shfl_xor(p, 32);
        if (q == 0) res0 = p;
        else if (q == 1) res1 = p;
        else if (q == 2) res2 = p;
        else res3 = p;
    }

    // lane l stores sample base+l  (= iter q==c, sample m) : fully coalesced
    float v = res0;
    if (c == 1) v = res1;
    if (c == 2) v = res2;
    if (c == 3) v = res3;
    v += b3;
    const float sg = 1.f / (1.f + __expf(-v));
    const int e_s = base + lane;
    const int s2  = e_s / 100000;
    const int r2  = e_s - s2 * 100000;
    out[(size_t)s2 * OUT_ROW + 400 + r2] = sg;
}

extern "C" void kernel_launch(void* const* d_in, const int* in_sizes, int n_in,
                              void* d_out, int out_size, void* d_ws, size_t ws_size,
                              hipStream_t stream) {
    (void)in_sizes; (void)n_in; (void)out_size; (void)ws_size;
    const float* obs = (const float*)d_in[0];
    const float* mu  = (const float*)d_in[1];
    const float* Sig = (const float*)d_in[2];
    const int*   prm = (const int*)d_in[3];
    const float* W1  = (const float*)d_in[4];
    const float* b1  = (const float*)d_in[5];
    const float* W2  = (const float*)d_in[6];
    const float* b2  = (const float*)d_in[7];
    const float* W3  = (const float*)d_in[8];
    const float* b3  = (const float*)d_in[9];

    char* ws = (char*)d_ws;
    __half* qtab   = (__half*)(ws + QTAB_OFF);
    __half* w2frag = (__half*)(ws + W2FRAG_OFF);
    __half* b1h    = (__half*)(ws + B1H_OFF);
    float*  b2f    = (float*)(ws + B2F_OFF);
    float*  w3f    = (float*)(ws + W3F_OFF);
    float*  b3f    = (float*)(ws + B3F_OFF);
    float*  out    = (float*)d_out;

    hipLaunchKernelGGL(precompute_kernel, dim3(100), dim3(64), 0, stream,
                       obs, mu, Sig, W1, b1, W2, b2, W3, b3,
                       qtab, w2frag, b1h, b2f, w3f, b3f, out);
    hipLaunchKernelGGL(eval_kernel, dim3(6250), dim3(256), 0, stream,
                       prm, qtab, w2frag, b1h, b2f, w3f, b3f, out);
}

// Round 7
// 117.179 us; speedup vs baseline: 1.1090x; 1.1090x over previous
//
#include <hip/hip_runtime.h>
#include <hip/hip_fp16.h>

#define S_N 16
#define T_N 400
#define F_N 16
#define SF_N 250
#define G_N 4
#define OUT_ROW 100400   // 400 + 250*400

typedef _Float16 f16x8 __attribute__((ext_vector_type(8)));
typedef float    f32x4 __attribute__((ext_vector_type(4)));

union QU { uint4 u; f16x8 v; };

// ws layout (bytes), all 16B-aligned:
#define QTAB_OFF   0
#define W2FRAG_OFF 1638400   // 64 lanes * 8 f16  = 1024 B
#define B1H_OFF    1639424   // 32 f16            = 64 B
#define B2F_OFF    1639488   // 16 f32            = 64 B
#define W3F_OFF    1639552   // 16 f32            = 64 B
#define B3F_OFF    1639616   // 1 f32

// LDS: 1600 rows (g*400+t'), each padded to 5 uint4 (80 B, data in first 4)
#define LDS_U4     8000      // 128,000 B

// ---------------------------------------------------------------------------
// Kernel A: build q-table (fp16) + MFMA-ready weight frags, emit unshuffled
// outputs. grid 100 x 64.  (unchanged, proven)
// qtab[s][g][t][k] = sum_{j in grp g} (obs[s,t,j]-mu_j)*A[j][k],
//   A[j][k] = sum_i Sig[i][j]*W1[i][k]
// ---------------------------------------------------------------------------
__global__ __launch_bounds__(64) void precompute_kernel(
    const float* __restrict__ obs,   // (S,T,F)
    const float* __restrict__ mu,    // (F,1)
    const float* __restrict__ Sig,   // (F,F)
    const float* __restrict__ W1,    // (F,32)
    const float* __restrict__ b1,    // (32,)
    const float* __restrict__ W2,    // (32,16)
    const float* __restrict__ b2,    // (16,)
    const float* __restrict__ W3,    // (16,1)
    const float* __restrict__ b3,    // (1,)
    __half* __restrict__ qtab,
    __half* __restrict__ w2frag,     // 64*8 f16, A-frag layout for W2^T
    __half* __restrict__ b1h,        // 32 f16
    float* __restrict__ b2f,         // 16
    float* __restrict__ w3f,         // 16
    float* __restrict__ b3f,         // 1
    float* __restrict__ out)         // (S, OUT_ROW) f32
{
    __shared__ float sAm[512];
    __shared__ float sW2[512];
    __shared__ float sMu[16];
    __shared__ float sB1[32];
    __shared__ float sB2[16];
    __shared__ float sW3[16];
    __shared__ float sB3;

    const int tid = threadIdx.x;   // 0..63

    for (int e = tid; e < 512; e += 64) {
        int j = e >> 5, k = e & 31;
        float acc = 0.f;
        #pragma unroll
        for (int i = 0; i < 16; ++i)
            acc = fmaf(Sig[i * 16 + j], W1[i * 32 + k], acc);
        sAm[e] = acc;
        sW2[e] = W2[e];
    }
    if (tid < 16) sMu[tid] = mu[tid];
    if (tid < 32) sB1[tid] = b1[tid];
    if (tid < 16) sB2[tid] = b2[tid];
    if (tid < 16) sW3[tid] = W3[tid];
    if (tid == 0) sB3 = b3[0];
    __syncthreads();

    if (blockIdx.x == 0) {
        // A-frag for A = W2^T: lane l holds A[m=l&15][k=(l>>4)*8+j] = W2[k][m]
        {
            int n = tid & 15, cc = tid >> 4;
            #pragma unroll
            for (int j = 0; j < 8; ++j)
                w2frag[tid * 8 + j] = __float2half(sW2[(cc * 8 + j) * 16 + n]);
        }
        if (tid < 32) b1h[tid] = __float2half(sB1[tid]);
        if (tid < 16) b2f[tid] = sB2[tid];
        if (tid < 16) w3f[tid] = sW3[tid];
        if (tid == 0) b3f[0] = sB3;
    }

    const int gid = blockIdx.x * 64 + tid;   // 0..6399 == s*400+t
    const int s = gid / T_N;
    const int t = gid - s * T_N;

    float xm[16];
    {
        const float4* op = (const float4*)(obs + (size_t)gid * 16);
        float4 o0 = op[0], o1 = op[1], o2 = op[2], o3 = op[3];
        float v[16] = {o0.x, o0.y, o0.z, o0.w, o1.x, o1.y, o1.z, o1.w,
                       o2.x, o2.y, o2.z, o2.w, o3.x, o3.y, o3.z, o3.w};
        #pragma unroll
        for (int j = 0; j < 16; ++j) xm[j] = v[j] - sMu[j];
    }

    float h1[32];
    #pragma unroll
    for (int k = 0; k < 32; ++k) h1[k] = sB1[k];

    #pragma unroll
    for (int g = 0; g < 4; ++g) {
        float qg[32];
        #pragma unroll
        for (int k = 0; k < 32; ++k) {
            float a = xm[4 * g + 0] * sAm[(4 * g + 0) * 32 + k];
            a = fmaf(xm[4 * g + 1], sAm[(4 * g + 1) * 32 + k], a);
            a = fmaf(xm[4 * g + 2], sAm[(4 * g + 2) * 32 + k], a);
            a = fmaf(xm[4 * g + 3], sAm[(4 * g + 3) * 32 + k], a);
            qg[k] = a;
            h1[k] += a;
        }
        __half2* dst = (__half2*)(qtab + ((size_t)(s * 4 + g) * T_N + t) * 32);
        #pragma unroll
        for (int k2 = 0; k2 < 16; ++k2)
            dst[k2] = __floats2half2_rn(qg[2 * k2], qg[2 * k2 + 1]);
    }

    #pragma unroll
    for (int k = 0; k < 32; ++k) h1[k] = fmaxf(h1[k], 0.01f * h1[k]);

    float h2[16];
    #pragma unroll
    for (int j = 0; j < 16; ++j) h2[j] = sB2[j];
    #pragma unroll
    for (int k = 0; k < 32; ++k) {
        float a = h1[k];
        #pragma unroll
        for (int j = 0; j < 16; ++j) h2[j] = fmaf(a, sW2[k * 16 + j], h2[j]);
    }
    float acc = sB3;
    #pragma unroll
    for (int j = 0; j < 16; ++j) {
        float hj = fmaxf(h2[j], 0.01f * h2[j]);
        acc = fmaf(hj, sW3[j], acc);
    }
    out[(size_t)s * OUT_ROW + t] = 1.f / (1.f + __expf(-acc));
}

// ---------------------------------------------------------------------------
// Kernel B: LDS-staged gathers. grid 256 = (s, chunk of 6250 samples),
// block 1024 threads = 16 waves, exactly 1 block/CU (LDS 125 KiB).
// Stage q[s] (1600 rows x 64 B -> 80 B padded rows) into LDS once, then all
// gathers are ds_read_b128 (off the TA/TCP request-rate path, which capped
// rounds 2-6 at ~46 us ~= 25.6M lane-requests at 1/cyc/CU).
// ---------------------------------------------------------------------------
__global__ __launch_bounds__(1024, 4) void eval_kernel(
    const int* __restrict__ perm,        // (SF,G,S,T)
    const __half* __restrict__ qtab,     // (S,G,T,32) fp16
    const __half* __restrict__ w2frag,   // 64*8
    const __half* __restrict__ b1h,      // 32
    const float* __restrict__ b2f,       // 16
    const float* __restrict__ w3f,       // 16
    const float* __restrict__ b3p,       // 1
    float* __restrict__ out)             // (S, OUT_ROW)
{
    extern __shared__ uint4 smem[];      // 8000 uint4 = 128,000 B

    const int tid   = threadIdx.x;       // 0..1023
    const int s     = blockIdx.x >> 4;   // 16 blocks per s
    const int chunk = blockIdx.x & 15;
    const int j0b   = chunk * 6250;      // block's sample range [j0b, j0b+6250)

    // ---- stage q[s]: 1600 rows x 4 uint4 -> smem[row*5 + cc] ----
    const uint4* qsrc = (const uint4*)(qtab + (size_t)s * 1600 * 32);
    for (int e = tid; e < 6400; e += 1024) {
        int r = e >> 2, cc = e & 3;
        smem[r * 5 + cc] = qsrc[e];
    }
    __syncthreads();

    const int lane = tid & 63;
    const int wv   = tid >> 6;           // wave 0..15
    const int m    = lane & 15;          // sample-in-group (B col)
    const int c    = lane >> 4;          // k-chunk / quad

    const f16x8 afrag = *(const f16x8*)(w2frag + lane * 8);
    const f16x8 b1v   = *(const f16x8*)(b1h + c * 8);
    const float4 b2v  = *(const float4*)(b2f + c * 4);
    const float4 w3v  = *(const float4*)(w3f + c * 4);
    const float  b3   = b3p[0];

    for (int tile = wv; tile < 98; tile += 16) {
        const int jt = j0b + tile * 64;

        // perm indices: lane (m,c) loads all 4 groups of its sample directly
        // (4 lanes share each address -> 1 line per 16 samples)
        int idx[4][4];   // [q][g]
        #pragma unroll
        for (int q = 0; q < 4; ++q) {
            int j = jt + q * 16 + m;
            int jc = j0b + 6249;
            if (j < jc) jc = j;          // clamp (partial last tile)
            const int sf = jc / 400;
            const int t  = jc - sf * 400;
            const int pb = sf * 25600 + s * 400 + t;
            #pragma unroll
            for (int g = 0; g < 4; ++g)
                idx[q][g] = perm[pb + g * 6400];
        }

        float res0, res1, res2, res3;
        #pragma unroll
        for (int q = 0; q < 4; ++q) {
            QU a0, a1, a2, a3;
            a0.u = smem[(idx[q][0]         ) * 5 + c];
            a1.u = smem[( 400 + idx[q][1]  ) * 5 + c];
            a2.u = smem[( 800 + idx[q][2]  ) * 5 + c];
            a3.u = smem[(1200 + idx[q][3]  ) * 5 + c];

            f16x8 h = (a0.v + a1.v) + (a2.v + a3.v) + b1v;
            #pragma unroll
            for (int k = 0; k < 8; ++k) {
                _Float16 x = h[k];
                _Float16 y = x * (_Float16)0.01f;
                h[k] = x > y ? x : y;    // leaky relu -> v_(pk_)max_f16
            }

            f32x4 acc = {0.f, 0.f, 0.f, 0.f};
            acc = __builtin_amdgcn_mfma_f32_16x16x32_f16(afrag, h, acc, 0, 0, 0);

            float p;
            {
                float v0 = acc[0] + b2v.x; v0 = fmaxf(v0, 0.01f * v0); p = v0 * w3v.x;
                float v1 = acc[1] + b2v.y; v1 = fmaxf(v1, 0.01f * v1); p = fmaf(v1, w3v.y, p);
                float v2 = acc[2] + b2v.z; v2 = fmaxf(v2, 0.01f * v2); p = fmaf(v2, w3v.z, p);
                float v3 = acc[3] + b2v.w; v3 = fmaxf(v3, 0.01f * v3); p = fmaf(v3, w3v.w, p);
            }
            p += __shfl_xor(p, 16);
            p += __shfl_xor(p, 32);
            if (q == 0) res0 = p;
            else if (q == 1) res1 = p;
            else if (q == 2) res2 = p;
            else res3 = p;
        }

        // lane l holds sample jt+l's value in res[c(l)] (round q == c)
        float v = res0;
        if (c == 1) v = res1;
        if (c == 2) v = res2;
        if (c == 3) v = res3;
        v += b3;
        const float sg = 1.f / (1.f + __expf(-v));
        const int j = jt + lane;
        if (j < j0b + 6250)
            out[(size_t)s * OUT_ROW + 400 + j] = sg;
    }
}

extern "C" void kernel_launch(void* const* d_in, const int* in_sizes, int n_in,
                              void* d_out, int out_size, void* d_ws, size_t ws_size,
                              hipStream_t stream) {
    (void)in_sizes; (void)n_in; (void)out_size; (void)ws_size;
    const float* obs = (const float*)d_in[0];
    const float* mu  = (const float*)d_in[1];
    const float* Sig = (const float*)d_in[2];
    const int*   prm = (const int*)d_in[3];
    const float* W1  = (const float*)d_in[4];
    const float* b1  = (const float*)d_in[5];
    const float* W2  = (const float*)d_in[6];
    const float* b2  = (const float*)d_in[7];
    const float* W3  = (const float*)d_in[8];
    const float* b3  = (const float*)d_in[9];

    char* ws = (char*)d_ws;
    __half* qtab   = (__half*)(ws + QTAB_OFF);
    __half* w2frag = (__half*)(ws + W2FRAG_OFF);
    __half* b1h    = (__half*)(ws + B1H_OFF);
    float*  b2f    = (float*)(ws + B2F_OFF);
    float*  w3f    = (float*)(ws + W3F_OFF);
    float*  b3f    = (float*)(ws + B3F_OFF);
    float*  out    = (float*)d_out;

    // allow >64 KiB dynamic LDS (no-op if already permitted)
    (void)hipFuncSetAttribute((const void*)eval_kernel,
                              hipFuncAttributeMaxDynamicSharedMemorySize,
                              LDS_U4 * 16);

    hipLaunchKernelGGL(precompute_kernel, dim3(100), dim3(64), 0, stream,
                       obs, mu, Sig, W1, b1, W2, b2, W3, b3,
                       qtab, w2frag, b1h, b2f, w3f, b3f, out);
    hipLaunchKernelGGL(eval_kernel, dim3(256), dim3(1024), LDS_U4 * 16, stream,
                       prm, qtab, w2frag, b1h, b2f, w3f, b3f, out);
}